// Round 4
// baseline (92.040 us; speedup 1.0000x reference)
//
#include <hip/hip_runtime.h>
#include <math.h>

#define H_FULL 2160
#define W_FULL 3840
#define H_D    1080
#define W_D    1920
#define KLEN   17
#define INV_K2 (1.0f/289.0f)

typedef float f32x4 __attribute__((ext_vector_type(4)));

#if __has_builtin(__builtin_amdgcn_logf)
#define FAST_LOG2(x) __builtin_amdgcn_logf(x)
#else
#define FAST_LOG2(x) log2f(x)
#endif
#if __has_builtin(__builtin_amdgcn_exp2f)
#define FAST_EXP2(x) __builtin_amdgcn_exp2f(x)
#else
#define FAST_EXP2(x) exp2f(x)
#endif
#if __has_builtin(__builtin_amdgcn_rcpf)
#define FAST_RCP(x) __builtin_amdgcn_rcpf(x)
#else
#define FAST_RCP(x) (1.0f/(x))
#endif

static __device__ __forceinline__ int refl(int i, int n) {
    if (i < 0) i = -i;
    else if (i >= n) i = 2*n - 2 - i;
    return i;
}
static __device__ __forceinline__ float lum(float r, float g, float b) {
    return 0.2126f*r + 0.7152f*g + 0.0722f*b;
}
static __device__ __forceinline__ float lg(float y) {
    return FAST_LOG2(fmaxf(y, 1e-6f));
}
static __device__ __forceinline__ void nt_store4(float* p, float a, float b,
                                                 float c, float d) {
    f32x4 v; v.x = a; v.y = b; v.z = c; v.w = d;
    __builtin_nontemporal_store(v, (f32x4*)p);
}

// K1: luma + log2 + exact 2x2-average downsample. 2 outputs/thread, float4 loads.
__global__ __launch_bounds__(256) void k_down(const float* __restrict__ x,
                                              float* __restrict__ I) {
    int t = blockIdx.x * 256 + threadIdx.x;     // 0 .. 1,036,799
    int p = t * 2;
    int i = p / W_D;
    int j = p - i * W_D;                        // even
    const float4* r0 = (const float4*)(x + ((size_t)(2*i)   * W_FULL + 2*j) * 3);
    const float4* r1 = (const float4*)(x + ((size_t)(2*i+1) * W_FULL + 2*j) * 3);
    float4 a0 = r0[0], a1 = r0[1], a2 = r0[2];
    float4 b0 = r1[0], b1 = r1[1], b2 = r1[2];
    float y00 = lum(a0.x,a0.y,a0.z), y01 = lum(a0.w,a1.x,a1.y);
    float y02 = lum(a1.z,a1.w,a2.x), y03 = lum(a2.y,a2.z,a2.w);
    float y10 = lum(b0.x,b0.y,b0.z), y11 = lum(b0.w,b1.x,b1.y);
    float y12 = lum(b1.z,b1.w,b2.x), y13 = lum(b2.y,b2.z,b2.w);
    float o0 = 0.25f * (lg(y00)+lg(y01)+lg(y10)+lg(y11));
    float o1 = 0.25f * (lg(y02)+lg(y03)+lg(y12)+lg(y13));
    *(float2*)(I + (size_t)i * W_D + j) = make_float2(o0, o1);
}

// K2: fused guided filter + tone map (round-0 champion) with:
//  - phase-B x data register-prefetched at entry (overlaps the filter phase),
//  - unrolled, predicated halo loads (load-level parallelism),
//  - non-temporal stores for out (never re-read; keep L3 for x/I).
__global__ __launch_bounds__(512, 6) void k_fused3(const float* __restrict__ I,
                                                   const float* __restrict__ x,
                                                   float* __restrict__ out) {
    __shared__ char lds[52088];
    float*  sIc   = (float*) (lds);             // 34x35 f   (4,760B)  live t2..B
    float*  sIf   = (float*) (lds + 4760);      // 66x67 f   (17,688B) live t1..t2
    float2* ab    = (float2*)(lds + 4760);      // 50x51 f2  (20,400B) live t3..t4 (over sIf)
    float2* hI    = (float2*)(lds + 25160);     // 66x51 f2  (26,928B) live t2..t3
    float2* hab   = (float2*)(lds + 25160);     // 50x35 f2  (14,000B) live t4..t5 (over hI)
    float*  baseL = (float*) (lds + 39160);     // 34x35 f   (4,760B)  live t5..B

    int tx0 = blockIdx.x * 32;          // base-tile col origin (downsampled coords)
    int ty0 = blockIdx.y * 32;          // base-tile row origin
    int tid = threadIdx.x;

    // ---- phase-B geometry + register prefetch of x (issued before phase A) ----
    int q  = tid & 15;                  // col group
    int r  = tid >> 4;                  // 0..31
    int j0 = tx0 * 2 + q * 4;
    int oy0 = ty0 * 2 + r;
    int oy1 = oy0 + 32;
    float4 pre[2][3];
    #pragma unroll
    for (int s = 0; s < 2; ++s)
        #pragma unroll
        for (int m = 0; m < 3; ++m)
            pre[s][m] = make_float4(0.f, 0.f, 0.f, 0.f);
    if (oy0 < H_FULL) {
        const float4* p0 = (const float4*)(x + ((size_t)oy0 * W_FULL + j0) * 3);
        pre[0][0] = p0[0]; pre[0][1] = p0[1]; pre[0][2] = p0[2];
    }
    if (oy1 < H_FULL) {
        const float4* p1 = (const float4*)(x + ((size_t)oy1 * W_FULL + j0) * 3);
        pre[1][0] = p1[0]; pre[1][1] = p1[1]; pre[1][2] = p1[2];
    }

    // stage 1: load 66x66 I halo (reflect), pitch 67 — unrolled, 9 independent loads
    #pragma unroll
    for (int it = 0; it < 9; ++it) {
        int e = tid + it * 512;
        if (e < 66 * 66) {
            int rr = e / 66, cc = e - rr * 66;
            sIf[rr * 67 + cc] =
                I[(size_t)refl(ty0 - 17 + rr, H_D) * W_D + refl(tx0 - 17 + cc, W_D)];
        }
    }
    __syncthreads();

    // stage 2: horizontal 17-sums of (I, I*I): 66 rows x 50 cols, 5 runs of 10/row
    if (tid < 330) {
        int rr = tid / 5, run = tid - (tid / 5) * 5;
        int c0 = run * 10;
        const float* p = &sIf[rr * 67 + c0];
        float s1 = 0.f, s2 = 0.f;
        #pragma unroll
        for (int k = 0; k < KLEN; ++k) { float v = p[k]; s1 += v; s2 += v * v; }
        float2* o = &hI[rr * 51 + c0];
        o[0] = make_float2(s1, s2);
        #pragma unroll
        for (int m = 1; m < 10; ++m) {
            float vo = p[m - 1], vi = p[m + 16];
            s1 += vi - vo;
            s2 += vi * vi - vo * vo;
            o[m] = make_float2(s1, s2);
        }
    }
    // concurrent: copy center I (34x34, rows/cols 16..49) into sIc (reads sIf only)
    #pragma unroll
    for (int it = 0; it < 3; ++it) {
        int e = tid + it * 512;
        if (e < 34 * 34) {
            int rr = e / 34, cc = e - rr * 34;
            sIc[rr * 35 + cc] = sIf[(rr + 16) * 67 + (cc + 16)];
        }
    }
    __syncthreads();

    // stage 3: vertical 17-sums -> (a,b) on 50x50, 5 runs of 10 rows (writes over sIf)
    if (tid < 250) {
        int c = tid % 50, run = tid / 50;
        int r0 = run * 10;
        const float2* p = &hI[r0 * 51 + c];
        float s1 = 0.f, s2 = 0.f;
        #pragma unroll
        for (int k = 0; k < KLEN; ++k) { float2 v = p[k * 51]; s1 += v.x; s2 += v.y; }
        float2* o = &ab[r0 * 51 + c];
        #pragma unroll
        for (int m = 0; m < 10; ++m) {
            if (m) {
                float2 vi = p[(m + 16) * 51], vo = p[(m - 1) * 51];
                s1 += vi.x - vo.x;
                s2 += vi.y - vo.y;
            }
            float mI  = s1 * INV_K2;
            float mII = s2 * INV_K2;
            float var = mII - mI * mI;
            float av  = var / (var + 1e-3f);
            o[m * 51] = make_float2(av, mI - av * mI);
        }
    }
    __syncthreads();

    // stage 4: horizontal 17-sums of (a,b): 50 rows x 34 cols, runs 9/9/8/8 (over hI)
    if (tid < 200) {
        int rr = tid % 50, run = tid / 50;
        int c0  = (run < 2) ? run * 9 : 18 + (run - 2) * 8;
        int len = (run < 2) ? 9 : 8;
        const float2* p = &ab[rr * 51 + c0];
        float sa = 0.f, sb = 0.f;
        #pragma unroll
        for (int k = 0; k < KLEN; ++k) { float2 v = p[k]; sa += v.x; sb += v.y; }
        float2* o = &hab[rr * 35 + c0];
        o[0] = make_float2(sa, sb);
        #pragma unroll
        for (int m = 1; m < 9; ++m) {
            if (m < len) {
                float2 vi = p[m + 16], vo = p[m - 1];
                sa += vi.x - vo.x;
                sb += vi.y - vo.y;
                o[m] = make_float2(sa, sb);
            }
        }
    }
    __syncthreads();

    // stage 5: vertical 17-sums -> baseL 34x34, runs 9/9/8/8 rows; combine with sIc
    if (tid < 136) {
        int cc = tid % 34, run = tid / 34;
        int r0  = (run < 2) ? run * 9 : 18 + (run - 2) * 8;
        int len = (run < 2) ? 9 : 8;
        const float2* p = &hab[r0 * 35 + cc];
        float sa = 0.f, sb = 0.f;
        #pragma unroll
        for (int k = 0; k < KLEN; ++k) { float2 v = p[k * 35]; sa += v.x; sb += v.y; }
        #pragma unroll
        for (int m = 0; m < 9; ++m) {
            if (m < len) {
                if (m) {
                    float2 vi = p[(m + 16) * 35], vo = p[(m - 1) * 35];
                    sa += vi.x - vo.x;
                    sb += vi.y - vo.y;
                }
                int br = r0 + m;
                baseL[br * 35 + cc] =
                    (sa * INV_K2) * sIc[br * 35 + cc] + sb * INV_K2;
            }
        }
    }
    __syncthreads();

    // phase B: tone-map 64x64 output region from prefetched registers
    int gc0 = tx0 + 2 * q - 1;
    int l0 = max(gc0, 0) - (tx0 - 1);
    int l1 = 2 * q + 1, l2 = 2 * q + 2;
    int l3 = min(gc0 + 3, W_D - 1) - (tx0 - 1);

    #pragma unroll
    for (int s = 0; s < 2; ++s) {
        int oy = ty0 * 2 + r + s * 32;
        if (oy < H_FULL) {
            int y0g = (oy - 1) >> 1;
            int ly0 = max(y0g, 0) - (ty0 - 1);
            int ly1 = min(y0g + 1, H_D - 1) - (ty0 - 1);
            float wy = (oy & 1) ? 0.25f : 0.75f;
            const float* b0r = &baseL[ly0 * 35];
            const float* b1r = &baseL[ly1 * 35];
            float v0 = b0r[l0] + (b1r[l0] - b0r[l0]) * wy;
            float v1 = b0r[l1] + (b1r[l1] - b0r[l1]) * wy;
            float v2 = b0r[l2] + (b1r[l2] - b0r[l2]) * wy;
            float v3 = b0r[l3] + (b1r[l3] - b0r[l3]) * wy;
            float Yb[4];
            Yb[0] = v0 + (v1 - v0) * 0.75f;
            Yb[1] = v1 + (v2 - v1) * 0.25f;
            Yb[2] = v1 + (v2 - v1) * 0.75f;
            Yb[3] = v2 + (v3 - v2) * 0.25f;

            float4 q0 = pre[s][0], q1 = pre[s][1], q2 = pre[s][2];
            float rgb[12] = {q0.x,q0.y,q0.z,q0.w, q1.x,q1.y,q1.z,q1.w, q2.x,q2.y,q2.z,q2.w};
            float res[12];
            #pragma unroll
            for (int k = 0; k < 4; ++k) {
                float rr = rgb[3*k], gg = rgb[3*k+1], bb = rgb[3*k+2];
                float Y = lum(rr, gg, bb);
                float sc = fmaxf(Y, 1e-6f) * FAST_EXP2(-0.3f * Yb[k]) * FAST_RCP(Y + 1e-4f);
                res[3*k]   = fminf(fmaxf(rr * sc, 0.f), 1.f);
                res[3*k+1] = fminf(fmaxf(gg * sc, 0.f), 1.f);
                res[3*k+2] = fminf(fmaxf(bb * sc, 0.f), 1.f);
            }
            size_t off = ((size_t)oy * W_FULL + j0) * 3;
            float* po = out + off;
            nt_store4(po + 0, res[0], res[1], res[2],  res[3]);
            nt_store4(po + 4, res[4], res[5], res[6],  res[7]);
            nt_store4(po + 8, res[8], res[9], res[10], res[11]);
        }
    }
}

extern "C" void kernel_launch(void* const* d_in, const int* in_sizes, int n_in,
                              void* d_out, int out_size, void* d_ws, size_t ws_size,
                              hipStream_t stream) {
    (void)in_sizes; (void)n_in; (void)out_size; (void)ws_size;
    const float* x = (const float*)d_in[0];
    float* out = (float*)d_out;
    float* I = (float*)d_ws;      // Y_log_down, 8.3 MB, rewritten every call

    k_down  <<<dim3(4050, 1, 1), dim3(256, 1, 1), 0, stream>>>(x, I);
    k_fused3<<<dim3(60, 34, 1),  dim3(512, 1, 1), 0, stream>>>(I, x, out);
}

// Round 5
// 74.481 us; speedup vs baseline: 1.2358x; 1.2358x over previous
//
#include <hip/hip_runtime.h>
#include <math.h>

#define H_FULL 2160
#define W_FULL 3840
#define H_D    1080
#define W_D    1920
#define KLEN   17
#define INV_K2 (1.0f/289.0f)

#if __has_builtin(__builtin_amdgcn_logf)
#define FAST_LOG2(x) __builtin_amdgcn_logf(x)
#else
#define FAST_LOG2(x) log2f(x)
#endif
#if __has_builtin(__builtin_amdgcn_exp2f)
#define FAST_EXP2(x) __builtin_amdgcn_exp2f(x)
#else
#define FAST_EXP2(x) exp2f(x)
#endif
#if __has_builtin(__builtin_amdgcn_rcpf)
#define FAST_RCP(x) __builtin_amdgcn_rcpf(x)
#else
#define FAST_RCP(x) (1.0f/(x))
#endif

static __device__ __forceinline__ int refl(int i, int n) {
    if (i < 0) i = -i;
    else if (i >= n) i = 2*n - 2 - i;
    return i;
}
static __device__ __forceinline__ float lum(float r, float g, float b) {
    return 0.2126f*r + 0.7152f*g + 0.0722f*b;
}
static __device__ __forceinline__ float lg(float y) {
    return FAST_LOG2(fmaxf(y, 1e-6f));
}

// K1: luma + log2 + exact 2x2-average downsample. 2 outputs/thread, float4 loads.
__global__ __launch_bounds__(256) void k_down(const float* __restrict__ x,
                                              float* __restrict__ I) {
    int t = blockIdx.x * 256 + threadIdx.x;     // 0 .. 1,036,799
    int p = t * 2;
    int i = p / W_D;
    int j = p - i * W_D;                        // even
    const float4* r0 = (const float4*)(x + ((size_t)(2*i)   * W_FULL + 2*j) * 3);
    const float4* r1 = (const float4*)(x + ((size_t)(2*i+1) * W_FULL + 2*j) * 3);
    float4 a0 = r0[0], a1 = r0[1], a2 = r0[2];
    float4 b0 = r1[0], b1 = r1[1], b2 = r1[2];
    float y00 = lum(a0.x,a0.y,a0.z), y01 = lum(a0.w,a1.x,a1.y);
    float y02 = lum(a1.z,a1.w,a2.x), y03 = lum(a2.y,a2.z,a2.w);
    float y10 = lum(b0.x,b0.y,b0.z), y11 = lum(b0.w,b1.x,b1.y);
    float y12 = lum(b1.z,b1.w,b2.x), y13 = lum(b2.y,b2.z,b2.w);
    float o0 = 0.25f * (lg(y00)+lg(y01)+lg(y10)+lg(y11));
    float o1 = 0.25f * (lg(y02)+lg(y03)+lg(y12)+lg(y13));
    *(float2*)(I + (size_t)i * W_D + j) = make_float2(o0, o1);
}

// K2: fused guided filter + tone map. Same arithmetic/geometry as the 69.8us
// champion, but: stage-2/5 read I directly from global (L2/L3-hot) instead of
// staging a 66x66 halo in LDS, and ab/hab are overlaid onto dead hI rows.
// LDS 52.2KB -> 38.9KB => 4 blocks/CU (32 waves/CU) instead of 3.
__global__ __launch_bounds__(512, 8) void k_fused4(const float* __restrict__ I,
                                                   const float* __restrict__ x,
                                                   float* __restrict__ out) {
    __shared__ char lds[38928];
    // region1 (0..12000):
    float2* abLo  = (float2*)(lds);            // ab rows 0..29: 30x50 f2 (12,000B), live t2..t4
    float*  baseL = (float*) (lds);            // 34x35 f (4,760B), live t5..B (over abLo)
    // region2 (12000..38928):
    float2* hI    = (float2*)(lds + 12000);    // 66x51 f2 (26,928B), live t1..t3b
    float2* abHi  = (float2*)(lds + 12000);    // ab rows 30..49: 20x50 f2 (8,000B), over hI rows 0..19
    float2* hab   = (float2*)(lds + 20000);    // 50x35 f2 (14,000B), over hI rows 20..54, live t4..t5

    int tx0 = blockIdx.x * 32;          // base-tile col origin (downsampled coords)
    int ty0 = blockIdx.y * 32;          // base-tile row origin
    int tid = threadIdx.x;
    bool xedge = (tx0 < 17) || (tx0 > W_D - 51);   // needs col reflection in x

    // stage 2 (entry stage): horizontal 17-sums of (I, I*I) straight from global.
    // 66 rows x 50 cols, 5 runs of 10/row -> 330 threads.
    if (tid < 330) {
        int r = tid / 5, run = tid - (tid / 5) * 5;
        int c0 = run * 10;
        int grow = refl(ty0 - 17 + r, H_D);
        const float* gI = I + (size_t)grow * W_D;
        int gc = tx0 - 17 + c0;
        float keep[9];
        float s1 = 0.f, s2 = 0.f;
        #pragma unroll
        for (int k = 0; k < 9; ++k) {
            int col = gc + k; if (xedge) col = refl(col, W_D);
            float v = gI[col];
            keep[k] = v; s1 += v; s2 += v * v;
        }
        #pragma unroll
        for (int k = 9; k < 17; ++k) {
            int col = gc + k; if (xedge) col = refl(col, W_D);
            float v = gI[col];
            s1 += v; s2 += v * v;
        }
        float2* o = &hI[r * 51 + c0];
        o[0] = make_float2(s1, s2);
        #pragma unroll
        for (int m = 1; m < 10; ++m) {
            int col = gc + m + 16; if (xedge) col = refl(col, W_D);
            float vi = gI[col];
            float vo = keep[m - 1];
            s1 += vi - vo;
            s2 += vi * vi - vo * vo;
            o[m] = make_float2(s1, s2);
        }
    }
    __syncthreads();

    // stage 3a: vertical 17-sums -> (a,b) rows 0..29 (reads hI rows 0..45),
    // 250 threads, 5 runs of 6 rows. Writes region1 (abLo).
    if (tid < 250) {
        int c = tid % 50, run = tid / 50;
        int r0 = run * 6;
        const float2* p = &hI[r0 * 51 + c];
        float s1 = 0.f, s2 = 0.f;
        #pragma unroll
        for (int k = 0; k < KLEN; ++k) { float2 v = p[k * 51]; s1 += v.x; s2 += v.y; }
        #pragma unroll
        for (int m = 0; m < 6; ++m) {
            if (m) {
                float2 vi = p[(m + 16) * 51], vo = p[(m - 1) * 51];
                s1 += vi.x - vo.x;
                s2 += vi.y - vo.y;
            }
            float mI  = s1 * INV_K2;
            float mII = s2 * INV_K2;
            float var = mII - mI * mI;
            float av  = var / (var + 1e-3f);
            abLo[(r0 + m) * 50 + c] = make_float2(av, mI - av * mI);
        }
    }
    __syncthreads();

    // stage 3b: (a,b) rows 30..49 (reads hI rows 30..65), writes over hI rows 0..19
    // (retired by 3a's barrier). 250 threads, 5 runs of 4 rows.
    if (tid < 250) {
        int c = tid % 50, run = tid / 50;
        int r0 = 30 + run * 4;
        const float2* p = &hI[r0 * 51 + c];
        float s1 = 0.f, s2 = 0.f;
        #pragma unroll
        for (int k = 0; k < KLEN; ++k) { float2 v = p[k * 51]; s1 += v.x; s2 += v.y; }
        #pragma unroll
        for (int m = 0; m < 4; ++m) {
            if (m) {
                float2 vi = p[(m + 16) * 51], vo = p[(m - 1) * 51];
                s1 += vi.x - vo.x;
                s2 += vi.y - vo.y;
            }
            float mI  = s1 * INV_K2;
            float mII = s2 * INV_K2;
            float var = mII - mI * mI;
            float av  = var / (var + 1e-3f);
            abHi[(r0 + m - 30) * 50 + c] = make_float2(av, mI - av * mI);
        }
    }
    __syncthreads();

    // stage 4: horizontal 17-sums of (a,b): 50 rows x 34 cols, runs 9/9/8/8.
    // Writes hab (over dead hI rows 20..54).
    if (tid < 200) {
        int rr = tid % 50, run = tid / 50;
        int c0  = (run < 2) ? run * 9 : 18 + (run - 2) * 8;
        int len = (run < 2) ? 9 : 8;
        const float2* row = (rr < 30) ? &abLo[rr * 50] : &abHi[(rr - 30) * 50];
        const float2* p = row + c0;
        float sa = 0.f, sb = 0.f;
        #pragma unroll
        for (int k = 0; k < KLEN; ++k) { float2 v = p[k]; sa += v.x; sb += v.y; }
        float2* o = &hab[rr * 35 + c0];
        o[0] = make_float2(sa, sb);
        #pragma unroll
        for (int m = 1; m < 9; ++m) {
            if (m < len) {
                float2 vi = p[m + 16], vo = p[m - 1];
                sa += vi.x - vo.x;
                sb += vi.y - vo.y;
                o[m] = make_float2(sa, sb);
            }
        }
    }
    __syncthreads();

    // stage 5: vertical 17-sums -> baseL 34x34 (over dead abLo), runs 9/9/8/8;
    // combine with center I read directly from global.
    if (tid < 136) {
        int cc = tid % 34, run = tid / 34;
        int r0  = (run < 2) ? run * 9 : 18 + (run - 2) * 8;
        int len = (run < 2) ? 9 : 8;
        int gcol = tx0 - 1 + cc;
        if (gcol < 0) gcol = -gcol;
        else if (gcol >= W_D) gcol = 2 * W_D - 2 - gcol;
        const float2* p = &hab[r0 * 35 + cc];
        float sa = 0.f, sb = 0.f;
        #pragma unroll
        for (int k = 0; k < KLEN; ++k) { float2 v = p[k * 35]; sa += v.x; sb += v.y; }
        #pragma unroll
        for (int m = 0; m < 9; ++m) {
            if (m < len) {
                if (m) {
                    float2 vi = p[(m + 16) * 35], vo = p[(m - 1) * 35];
                    sa += vi.x - vo.x;
                    sb += vi.y - vo.y;
                }
                int br = r0 + m;
                int grow = refl(ty0 - 1 + br, H_D);
                float Ic = I[(size_t)grow * W_D + gcol];
                baseL[br * 35 + cc] = (sa * INV_K2) * Ic + sb * INV_K2;
            }
        }
    }
    __syncthreads();

    // phase B: tone-map 64x64 output region; 512 threads x (2 rows of 4 px)
    int q  = tid & 15;                  // col group
    int r  = tid >> 4;                  // 0..31
    int j0 = tx0 * 2 + q * 4;
    int gc0 = tx0 + 2 * q - 1;
    int l0 = max(gc0, 0) - (tx0 - 1);
    int l1 = 2 * q + 1, l2 = 2 * q + 2;
    int l3 = min(gc0 + 3, W_D - 1) - (tx0 - 1);

    #pragma unroll
    for (int s = 0; s < 2; ++s) {
        int oy = ty0 * 2 + r + s * 32;
        if (oy < H_FULL) {
            int y0g = (oy - 1) >> 1;
            int ly0 = max(y0g, 0) - (ty0 - 1);
            int ly1 = min(y0g + 1, H_D - 1) - (ty0 - 1);
            float wy = (oy & 1) ? 0.25f : 0.75f;
            const float* b0r = &baseL[ly0 * 35];
            const float* b1r = &baseL[ly1 * 35];
            float v0 = b0r[l0] + (b1r[l0] - b0r[l0]) * wy;
            float v1 = b0r[l1] + (b1r[l1] - b0r[l1]) * wy;
            float v2 = b0r[l2] + (b1r[l2] - b0r[l2]) * wy;
            float v3 = b0r[l3] + (b1r[l3] - b0r[l3]) * wy;
            float Yb[4];
            Yb[0] = v0 + (v1 - v0) * 0.75f;
            Yb[1] = v1 + (v2 - v1) * 0.25f;
            Yb[2] = v1 + (v2 - v1) * 0.75f;
            Yb[3] = v2 + (v3 - v2) * 0.25f;

            size_t off = ((size_t)oy * W_FULL + j0) * 3;
            const float4* px = (const float4*)(x + off);
            float4 q0 = px[0], q1 = px[1], q2 = px[2];
            float rgb[12] = {q0.x,q0.y,q0.z,q0.w, q1.x,q1.y,q1.z,q1.w, q2.x,q2.y,q2.z,q2.w};
            float res[12];
            #pragma unroll
            for (int k = 0; k < 4; ++k) {
                float rr = rgb[3*k], gg = rgb[3*k+1], bb = rgb[3*k+2];
                float Y = lum(rr, gg, bb);
                float sc = fmaxf(Y, 1e-6f) * FAST_EXP2(-0.3f * Yb[k]) * FAST_RCP(Y + 1e-4f);
                res[3*k]   = fminf(fmaxf(rr * sc, 0.f), 1.f);
                res[3*k+1] = fminf(fmaxf(gg * sc, 0.f), 1.f);
                res[3*k+2] = fminf(fmaxf(bb * sc, 0.f), 1.f);
            }
            float4* po = (float4*)(out + off);
            po[0] = make_float4(res[0], res[1], res[2],  res[3]);
            po[1] = make_float4(res[4], res[5], res[6],  res[7]);
            po[2] = make_float4(res[8], res[9], res[10], res[11]);
        }
    }
}

extern "C" void kernel_launch(void* const* d_in, const int* in_sizes, int n_in,
                              void* d_out, int out_size, void* d_ws, size_t ws_size,
                              hipStream_t stream) {
    (void)in_sizes; (void)n_in; (void)out_size; (void)ws_size;
    const float* x = (const float*)d_in[0];
    float* out = (float*)d_out;
    float* I = (float*)d_ws;      // Y_log_down, 8.3 MB, rewritten every call

    k_down  <<<dim3(4050, 1, 1), dim3(256, 1, 1), 0, stream>>>(x, I);
    k_fused4<<<dim3(60, 34, 1),  dim3(512, 1, 1), 0, stream>>>(I, x, out);
}